// Round 14
// baseline (247.056 us; speedup 1.0000x reference)
//
#include <hip/hip_runtime.h>
#include <hip/hip_bf16.h>

#define M_ 501
#define T_ 512
#define DT_ 0.01f

typedef __attribute__((ext_vector_type(8))) __bf16 bf16x8;
typedef __attribute__((ext_vector_type(4))) float f32x4;

static __device__ __forceinline__ unsigned int pack2(float a, float b) {
    __hip_bfloat16 ha = __float2bfloat16(a);
    __hip_bfloat16 hb = __float2bfloat16(b);
    unsigned short ua = __builtin_bit_cast(unsigned short, ha);
    unsigned short ub = __builtin_bit_cast(unsigned short, hb);
    return (unsigned int)ua | ((unsigned int)ub << 16);
}

// ---------------- P2: W1comb (1024 x 384) pre-swizzled into MFMA fragment order
// [((kg*24 + nt)*64 + lane)*8 + e] : k = kg*32 + (lane>>4)*8 + e, n = nt*16 + (lane&15)
__global__ void build_w(const float* __restrict__ Ew1, const float* __restrict__ bw1,
                        const float* __restrict__ nw1, __hip_bfloat16* __restrict__ Wswz) {
    int idx = blockIdx.x * 256 + threadIdx.x;       // total 32*24*64*8 = 393216
    if (idx >= 32 * 24 * 64 * 8) return;
    int e  = idx & 7;
    int l  = (idx >> 3) & 63;
    int t  = idx >> 9;
    int nt = t % 24, k0 = t / 24;
    int k  = k0 * 32 + ((l >> 4) << 3) + e;
    int n  = nt * 16 + (l & 15);
    float v = 0.f;
    if (n < 128)      { if (k < 2*M_)             v = Ew1[k * 128 + n]; }
    else if (n < 256) { if (k < 2*M_)             v = bw1[k * 128 + (n - 128)]; }
    else              { if (k >= M_ && k < 2*M_)  v = nw1[(k - M_) * 128 + (n - 256)]; }
    Wswz[idx] = __float2bfloat16(v);
}

// ---------------- Fused: stage X -> global Xt (k-major), barrier-free GEMM,
// epilogue, scan. 512 thr (8 waves), 64 rows/block, grid 512.
// Phase 1 (R12 staging machinery, global dest): thread (sr=tid>>3, su=tid&7),
// 16 chunks; loads are 8-rows x 8-lane-contiguous (8 lines/instr); store 16B
// to Xt[(k0*B + brow+sr)*32 + (cu&3)*8] (two 512B regions/wave = coalesced).
// Phase 2 (R3 structure): NO barriers, NO LDS. af = direct bf16x8 loads from
// the block's own 128KB Xt slice (L2-resident, 1KB/wave contiguous); W from
// L2 (402MB aggregate). Compiler pipelines freely. LDS total ~3.8KB.
__global__ __launch_bounds__(512, 2) void fused_all(
    const float* __restrict__ E, const float* __restrict__ nu,
    const __hip_bfloat16* __restrict__ Wswz, __hip_bfloat16* __restrict__ Xt,
    const float* __restrict__ Eb1, const float* __restrict__ bb1, const float* __restrict__ nb1,
    const float* __restrict__ Ew2, const float* __restrict__ bw2, const float* __restrict__ nw2,
    const float* __restrict__ Eb2, const float* __restrict__ bb2, const float* __restrict__ nb2,
    const float* __restrict__ e, const float* __restrict__ ed,
    float* __restrict__ stress, float* __restrict__ xiout, int B)
{
    const int tid = threadIdx.x;
    const int wid = tid >> 6, l = tid & 63;
    const int c = l & 15, g = l >> 4;
    const int brow = blockIdx.x * 64;

    __shared__ float cb1[384], cw2[384];
    __shared__ float lds_s[3][64];

    if (tid < 384) {
        int n = tid;
        cb1[n] = (n < 128) ? Eb1[n] : (n < 256) ? bb1[n - 128] : nb1[n - 256];
        cw2[n] = (n < 128) ? Ew2[n] : (n < 256) ? bw2[n - 128] : nw2[n - 256];
    }
    if (tid < 192) ((float*)lds_s)[tid] = 0.f;

    // ---- phase 1: stage this block's 64 rows into Xt (k-major, bf16) ----
    {
        const int sr = tid >> 3, su = tid & 7;       // row 0..63, lane-octet 0..7
        const size_t rb = (size_t)(brow + sr) * M_;
        for (int ch = 0; ch < 16; ++ch) {
            const int cu = ch * 8 + su;              // 0..127
            float f0, f1, f2, f3, f4, f5, f6, f7;
            const bool slow = (cu == 62) | (cu >= 124);
            if (!slow) {
                const float* src = (cu < 62) ? E : nu;
                const int off = (cu < 62) ? cu * 8 : cu * 8 - M_;
                const size_t s = rb + (size_t)off;
                const int o = (int)(s & 3);
                const f32x4* p = (const f32x4*)(src + (s & ~(size_t)3));
                f32x4 q0 = p[0], q1 = p[1], q2 = p[2];
                asm volatile("" : "+v"(q0), "+v"(q1), "+v"(q2));
                float g0=q0[0], g1=q0[1], g2=q0[2], g3=q0[3],
                      g4=q1[0], g5=q1[1], g6=q1[2], g7=q1[3],
                      g8=q2[0], g9=q2[1], g10=q2[2];
                const bool o2 = (o & 2) != 0, o1 = (o & 1) != 0;
                float u0 = o2?g2:g0, u1 = o2?g3:g1, u2 = o2?g4:g2, u3 = o2?g5:g3,
                      u4 = o2?g6:g4, u5 = o2?g7:g5, u6 = o2?g8:g6, u7 = o2?g9:g7,
                      u8 = o2?g10:g8;
                f0 = o1?u1:u0; f1 = o1?u2:u1; f2 = o1?u3:u2; f3 = o1?u4:u3;
                f4 = o1?u5:u4; f5 = o1?u6:u5; f6 = o1?u7:u6; f7 = o1?u8:u7;
            } else {
                const int kb = cu * 8;
                auto ldx = [&](int k) -> float {
                    return (k < M_) ? E[rb + k] : ((k < 2 * M_) ? nu[rb + k - M_] : 0.f);
                };
                f0 = ldx(kb+0); f1 = ldx(kb+1); f2 = ldx(kb+2); f3 = ldx(kb+3);
                f4 = ldx(kb+4); f5 = ldx(kb+5); f6 = ldx(kb+6); f7 = ldx(kb+7);
            }
            uint4 vv;
            vv.x = pack2(f0, f1); vv.y = pack2(f2, f3);
            vv.z = pack2(f4, f5); vv.w = pack2(f6, f7);
            *(uint4*)(Xt + ((size_t)(cu >> 2) * B + brow + sr) * 32 + (cu & 3) * 8) = vv;
        }
    }
    __threadfence();
    __syncthreads();

    // ---- phase 2: barrier-free GEMM ----
    const bf16x8* wbase = (const bf16x8*)Wswz;
    f32x4 acc[4][3];
    #pragma unroll
    for (int mi = 0; mi < 4; mi++)
        #pragma unroll
        for (int nt = 0; nt < 3; nt++) acc[mi][nt] = (f32x4){0.f, 0.f, 0.f, 0.f};

    for (int kg = 0; kg < 32; ++kg) {
        bf16x8 w[3];
        #pragma unroll
        for (int nt = 0; nt < 3; ++nt)
            w[nt] = wbase[(size_t)(kg * 24 + wid * 3 + nt) * 64 + l];
        bf16x8 af[4];
        #pragma unroll
        for (int mi = 0; mi < 4; ++mi)
            af[mi] = *(const bf16x8*)(Xt + ((size_t)kg * B + brow + c + mi * 16) * 32 + g * 8);
        #pragma unroll
        for (int nt = 0; nt < 3; ++nt)
            #pragma unroll
            for (int mi = 0; mi < 4; ++mi)
                acc[mi][nt] = __builtin_amdgcn_mfma_f32_16x16x32_bf16(w[nt], af[mi], acc[mi][nt], 0, 0, 0);
    }

    // ---- epilogue: hidden-units on reg axis -> cheap reduce ----
    float bv[12], wv[12];
    #pragma unroll
    for (int nt = 0; nt < 3; ++nt)
        #pragma unroll
        for (int r = 0; r < 4; ++r) {
            int nidx = (wid * 3 + nt) * 16 + g * 4 + r;
            bv[nt * 4 + r] = cb1[nidx];
            wv[nt * 4 + r] = cw2[nidx];
        }
    const int m_first = (wid * 3) >> 3, m_last = (wid * 3 + 2) >> 3;

    #pragma unroll
    for (int mi = 0; mi < 4; ++mi) {
        float s0 = 0.f, s1 = 0.f, s2 = 0.f;
        #pragma unroll
        for (int nt = 0; nt < 3; ++nt) {
            float p = 0.f;
            #pragma unroll
            for (int r = 0; r < 4; ++r) {
                float x = acc[mi][nt][r] + bv[nt * 4 + r];
                float h = fmaxf(x, 0.f) + __logf(1.f + __expf(-fabsf(x)));
                p += h * wv[nt * 4 + r];
            }
            int m = (wid * 3 + nt) >> 3;
            if (m == 0) s0 += p; else if (m == 1) s1 += p; else s2 += p;
        }
        auto red = [&](float v, int m) {
            v += __shfl_xor(v, 16);
            v += __shfl_xor(v, 32);
            if (l < 16) atomicAdd(&lds_s[m][mi * 16 + l], v);
        };
        if (m_first == 0) red(s0, 0);
        if (m_first <= 1 && m_last >= 1) red(s1, 1);
        if (m_last == 2) red(s2, 2);
    }
    __syncthreads();

    // ---- finalize per-row scalars in LDS ----
    if (tid < 64) {
        float s0 = lds_s[0][tid], s1 = lds_s[1][tid], s2 = lds_s[2][tid];
        lds_s[0][tid] = __expf(s0 + Eb2[0]);                      // Emod
        float mb = s1 + bb2[0];
        lds_s[1][tid] = mb * mb * (1.f / 40000.f);                // beta
        float mn = s2 + nb2[0];
        lds_s[2][tid] = __expf(mn * mn * (1.f / 40000.f));        // nuv
    }
    __syncthreads();

    // ---- fused scan: wave wid handles rows wid*8 .. wid*8+7 ----
    for (int i = 0; i < 8; ++i) {
        const int rr = wid * 8 + i;
        const int b = brow + rr;
        float Em = lds_s[0][rr], bt = lds_s[1][rr], nv = lds_s[2][rr];
        float cc = DT_ * bt;
        float a  = 1.f - cc;

        size_t base = (size_t)b * T_ + (size_t)l * 8;
        float4 e0 = *(const float4*)(e + base),  e1 = *(const float4*)(e + base + 4);
        float4 d0 = *(const float4*)(ed + base), d1 = *(const float4*)(ed + base + 4);
        float ev[8] = {e0.x, e0.y, e0.z, e0.w, e1.x, e1.y, e1.z, e1.w};
        float dv[8] = {d0.x, d0.y, d0.z, d0.w, d1.x, d1.y, d1.z, d1.w};

        float S = 0.f;
        #pragma unroll
        for (int j = 0; j < 8; j++) S = a * S + ev[j];
        float a2 = a * a, a4 = a2 * a2, A = a4 * a4;

        #pragma unroll
        for (int d = 1; d < 64; d <<= 1) {
            float Su = __shfl_up(S, d);
            float Au = __shfl_up(A, d);
            if (l >= d) { S = Su * A + S; A = Au * A; }
        }
        float Sp = __shfl_up(S, 1);
        float xi = (l == 0) ? 0.f : cc * Sp;

        float st[8], xo[8];
        #pragma unroll
        for (int j = 0; j < 8; j++) {
            xo[j] = xi;
            float qd = ev[j] - xi;
            st[j] = Em * ev[j] + qd + nv * dv[j];
            xi = xi + cc * qd;
        }
        *(float4*)(stress + base)     = (float4){st[0], st[1], st[2], st[3]};
        *(float4*)(stress + base + 4) = (float4){st[4], st[5], st[6], st[7]};
        *(float4*)(xiout + base)      = (float4){xo[0], xo[1], xo[2], xo[3]};
        *(float4*)(xiout + base + 4)  = (float4){xo[4], xo[5], xo[6], xo[7]};
    }
}

extern "C" void kernel_launch(void* const* d_in, const int* in_sizes, int n_in,
                              void* d_out, int out_size, void* d_ws, size_t ws_size,
                              hipStream_t stream) {
    const float* e   = (const float*)d_in[0];
    const float* ed  = (const float*)d_in[1];
    const float* E   = (const float*)d_in[2];
    const float* nu  = (const float*)d_in[3];
    const float* Ew1 = (const float*)d_in[4];
    const float* Eb1 = (const float*)d_in[5];
    const float* Ew2 = (const float*)d_in[6];
    const float* Eb2 = (const float*)d_in[7];
    const float* nw1 = (const float*)d_in[8];
    const float* nb1 = (const float*)d_in[9];
    const float* nw2 = (const float*)d_in[10];
    const float* nb2 = (const float*)d_in[11];
    const float* bw1 = (const float*)d_in[12];
    const float* bb1 = (const float*)d_in[13];
    const float* bw2 = (const float*)d_in[14];
    const float* bb2 = (const float*)d_in[15];

    int B = in_sizes[2] / M_;                       // 32768

    char* ws = (char*)d_ws;
    __hip_bfloat16* Wswz = (__hip_bfloat16*)ws;                       // 786432 B
    __hip_bfloat16* Xt   = (__hip_bfloat16*)(ws + 786432);            // B*1024*2 B

    float* stress = (float*)d_out;
    float* xiout  = stress + (size_t)B * T_;

    build_w<<<(1024 * 384 + 255) / 256, 256, 0, stream>>>(Ew1, bw1, nw1, Wswz);
    fused_all<<<B / 64, 512, 0, stream>>>(E, nu, Wswz, Xt, Eb1, bb1, nb1,
                                          Ew2, bw2, nw2, Eb2, bb2, nb2,
                                          e, ed, stress, xiout, B);
}

// Round 15
// 136.224 us; speedup vs baseline: 1.8136x; 1.8136x over previous
//
#include <hip/hip_runtime.h>
#include <hip/hip_bf16.h>

#define M_ 501
#define T_ 512
#define DT_ 0.01f

typedef __attribute__((ext_vector_type(8))) __bf16 bf16x8;
typedef __attribute__((ext_vector_type(4))) float f32x4;

static __device__ __forceinline__ unsigned int pack2(float a, float b) {
    __hip_bfloat16 ha = __float2bfloat16(a);
    __hip_bfloat16 hb = __float2bfloat16(b);
    unsigned short ua = __builtin_bit_cast(unsigned short, ha);
    unsigned short ub = __builtin_bit_cast(unsigned short, hb);
    return (unsigned int)ua | ((unsigned int)ub << 16);
}

// ---------------- P2: W1comb (1024 x 384) pre-swizzled into MFMA fragment order
// [((kg*24 + nt)*64 + lane)*8 + e] : k = kg*32 + (lane>>4)*8 + e, n = nt*16 + (lane&15)
__global__ void build_w(const float* __restrict__ Ew1, const float* __restrict__ bw1,
                        const float* __restrict__ nw1, __hip_bfloat16* __restrict__ Wswz) {
    int idx = blockIdx.x * 256 + threadIdx.x;       // total 32*24*64*8 = 393216
    if (idx >= 32 * 24 * 64 * 8) return;
    int e  = idx & 7;
    int l  = (idx >> 3) & 63;
    int t  = idx >> 9;
    int nt = t % 24, k0 = t / 24;
    int k  = k0 * 32 + ((l >> 4) << 3) + e;
    int n  = nt * 16 + (l & 15);
    float v = 0.f;
    if (n < 128)      { if (k < 2*M_)             v = Ew1[k * 128 + n]; }
    else if (n < 256) { if (k < 2*M_)             v = bw1[k * 128 + (n - 128)]; }
    else              { if (k >= M_ && k < 2*M_)  v = nw1[(k - M_) * 128 + (n - 256)]; }
    Wswz[idx] = __float2bfloat16(v);
}

// ---------------- Fused: GEMM (T4 counted-vmcnt pipeline) + epilogue + scan --
// 512 thr (8 waves), 64 rows/block, grid 512 (2 blocks/CU). BK=64 chunks (16).
// 3-deep LDS ring sA[3][64x64 bf16] (24KB) + 2 register stage-sets (qa/qb):
// stage loads issued 3 chunks ahead, finished (select+pack+ds_write) 2 ahead.
// Barriers are RAW s_barrier + lgkmcnt(0) only — in-flight stage VMEM crosses
// the barrier (T4); by first use every stage load is >=1.5 chunks old -> all
// vmcnt retirement is free. __syncthreads (vmcnt(0) drain) only in epilogue.
__global__ __launch_bounds__(512, 2) void fused_all(
    const float* __restrict__ E, const float* __restrict__ nu,
    const __hip_bfloat16* __restrict__ Wswz,
    const float* __restrict__ Eb1, const float* __restrict__ bb1, const float* __restrict__ nb1,
    const float* __restrict__ Ew2, const float* __restrict__ bw2, const float* __restrict__ nw2,
    const float* __restrict__ Eb2, const float* __restrict__ bb2, const float* __restrict__ nb2,
    const float* __restrict__ e, const float* __restrict__ ed,
    float* __restrict__ stress, float* __restrict__ xiout, int B)
{
    const int tid = threadIdx.x;
    const int wid = tid >> 6, l = tid & 63;
    const int c = l & 15, g = l >> 4;
    const int brow = blockIdx.x * 64;

    __shared__ __align__(16) unsigned char sAraw[3][64 * 128];    // 24 KB ring
    __shared__ float cb1[384], cw2[384];
    __shared__ float lds_s[3][64];

    if (tid < 384) {
        int n = tid;
        cb1[n] = (n < 128) ? Eb1[n] : (n < 256) ? bb1[n - 128] : nb1[n - 256];
        cw2[n] = (n < 128) ? Ew2[n] : (n < 256) ? bw2[n - 128] : nw2[n - 256];
    }
    if (tid < 192) ((float*)lds_s)[tid] = 0.f;

    // ---- staging machinery: 1 item/thread/chunk, two register sets ----
    const int sr = tid >> 3, su = tid & 7;           // row 0..63, col-octet 0..7
    const size_t rb = (size_t)(brow + sr) * M_;
    f32x4 qa0, qa1, qa2, qb0, qb1, qb2; int oa = 0, ob = 0;

    auto stage_load = [&](int ch, f32x4& r0, f32x4& r1, f32x4& r2, int& ro) {
        int cu = ch * 8 + su;
        bool slow = (cu == 62) | (cu >= 124);
        if (!slow) {
            const float* src = (cu < 62) ? E : nu;
            int off = (cu < 62) ? cu * 8 : cu * 8 - M_;
            size_t s = rb + (size_t)off;
            ro = (int)(s & 3);
            const f32x4* p = (const f32x4*)(src + (s & ~(size_t)3));
            r0 = p[0]; r1 = p[1]; r2 = p[2];
        } else {
            int kb = cu * 8;
            auto ldx = [&](int k) -> float {
                return (k < M_) ? E[rb + k] : ((k < 2 * M_) ? nu[rb + k - M_] : 0.f);
            };
            r0 = (f32x4){ldx(kb+0), ldx(kb+1), ldx(kb+2), ldx(kb+3)};
            r1 = (f32x4){ldx(kb+4), ldx(kb+5), ldx(kb+6), ldx(kb+7)};
            r2 = (f32x4){0.f, 0.f, 0.f, 0.f};
            ro = 0;
        }
    };
    auto stage_finish = [&](int nbuf, f32x4& r0, f32x4& r1, f32x4& r2, int& ro) {
        asm volatile("" : "+v"(r0), "+v"(r1), "+v"(r2));   // first use: vmcnt wait here (free: loads are old)
        float g0=r0[0], g1=r0[1], g2=r0[2], g3=r0[3],
              g4=r1[0], g5=r1[1], g6=r1[2], g7=r1[3],
              g8=r2[0], g9=r2[1], g10=r2[2];
        const bool o2 = (ro & 2) != 0, o1 = (ro & 1) != 0;
        float u0 = o2?g2:g0, u1 = o2?g3:g1, u2 = o2?g4:g2, u3 = o2?g5:g3,
              u4 = o2?g6:g4, u5 = o2?g7:g5, u6 = o2?g8:g6, u7 = o2?g9:g7,
              u8 = o2?g10:g8;
        float f0 = o1?u1:u0, f1 = o1?u2:u1, f2 = o1?u3:u2, f3 = o1?u4:u3,
              f4 = o1?u5:u4, f5 = o1?u6:u5, f6 = o1?u7:u6, f7 = o1?u8:u7;
        uint4 vv;
        vv.x = pack2(f0, f1); vv.y = pack2(f2, f3);
        vv.z = pack2(f4, f5); vv.w = pack2(f6, f7);
        unsigned bo = ((unsigned)sr << 7) + ((((unsigned)su) << 4) ^ (((unsigned)(sr & 7)) << 4));
        *(uint4*)(sAraw[nbuf] + bo) = vv;
    };

    const bf16x8* wbase = (const bf16x8*)Wswz;

    f32x4 acc[4][3];
    #pragma unroll
    for (int mi = 0; mi < 4; mi++)
        #pragma unroll
        for (int nt = 0; nt < 3; nt++) acc[mi][nt] = (f32x4){0.f, 0.f, 0.f, 0.f};

    auto compute = [&](int bufi, int ch) {
        #pragma unroll
        for (int kk = 0; kk < 2; ++kk) {
            const int kg = ch * 2 + kk;
            bf16x8 w[3];
            #pragma unroll
            for (int nt = 0; nt < 3; ++nt)
                w[nt] = wbase[(size_t)(kg * 24 + wid * 3 + nt) * 64 + l];
            bf16x8 af[4];
            #pragma unroll
            for (int mi = 0; mi < 4; ++mi) {
                int row = c + mi * 16;
                unsigned bo = ((unsigned)row << 7) +
                    ((((unsigned)kk << 6) + ((unsigned)g << 4)) ^ (((unsigned)(row & 7)) << 4));
                af[mi] = *(const bf16x8*)(sAraw[bufi] + bo);
            }
            #pragma unroll
            for (int nt = 0; nt < 3; ++nt)
                #pragma unroll
                for (int mi = 0; mi < 4; ++mi)
                    acc[mi][nt] = __builtin_amdgcn_mfma_f32_16x16x32_bf16(w[nt], af[mi], acc[mi][nt], 0, 0, 0);
        }
    };

    #define BAR() do {                                        \
        asm volatile("s_waitcnt lgkmcnt(0)" ::: "memory");    \
        __builtin_amdgcn_s_barrier();                         \
        __builtin_amdgcn_sched_barrier(0);                    \
    } while (0)

    // ---- prologue: fill buf0, buf1; stage(2) left in flight in qa ----
    stage_load(0, qa0, qa1, qa2, oa);
    stage_load(1, qb0, qb1, qb2, ob);
    stage_finish(0, qa0, qa1, qa2, oa);              // waits load(0) (once)
    stage_load(2, qa0, qa1, qa2, oa);
    stage_finish(1, qb0, qb1, qb2, ob);              // load(1) nearly done
    BAR();

    // ---- chunk loop: invariant at ch: q[ch&1] holds stage(ch+2) ----
    for (int ch = 0; ch < 16; ch += 2) {
        // even: finish-src qa, load-dst qb
        compute(ch % 3, ch);
        if (ch + 3 < 16) stage_load(ch + 3, qb0, qb1, qb2, ob);
        if (ch + 2 < 16) stage_finish((ch + 2) % 3, qa0, qa1, qa2, oa);
        BAR();
        // odd: finish-src qb, load-dst qa
        const int c1 = ch + 1;
        compute(c1 % 3, c1);
        if (c1 + 3 < 16) stage_load(c1 + 3, qa0, qa1, qa2, oa);
        if (c1 + 2 < 16) stage_finish((c1 + 2) % 3, qb0, qb1, qb2, ob);
        BAR();
    }
    #undef BAR

    // ---- epilogue: hidden-units on reg axis -> cheap reduce ----
    float bv[12], wv[12];
    #pragma unroll
    for (int nt = 0; nt < 3; ++nt)
        #pragma unroll
        for (int r = 0; r < 4; ++r) {
            int nidx = (wid * 3 + nt) * 16 + g * 4 + r;
            bv[nt * 4 + r] = cb1[nidx];
            wv[nt * 4 + r] = cw2[nidx];
        }
    const int m_first = (wid * 3) >> 3, m_last = (wid * 3 + 2) >> 3;

    #pragma unroll
    for (int mi = 0; mi < 4; ++mi) {
        float s0 = 0.f, s1 = 0.f, s2 = 0.f;
        #pragma unroll
        for (int nt = 0; nt < 3; ++nt) {
            float p = 0.f;
            #pragma unroll
            for (int r = 0; r < 4; ++r) {
                float x = acc[mi][nt][r] + bv[nt * 4 + r];
                float h = fmaxf(x, 0.f) + __logf(1.f + __expf(-fabsf(x)));
                p += h * wv[nt * 4 + r];
            }
            int m = (wid * 3 + nt) >> 3;
            if (m == 0) s0 += p; else if (m == 1) s1 += p; else s2 += p;
        }
        auto red = [&](float v, int m) {
            v += __shfl_xor(v, 16);
            v += __shfl_xor(v, 32);
            if (l < 16) atomicAdd(&lds_s[m][mi * 16 + l], v);
        };
        if (m_first == 0) red(s0, 0);
        if (m_first <= 1 && m_last >= 1) red(s1, 1);
        if (m_last == 2) red(s2, 2);
    }
    __syncthreads();

    // ---- finalize per-row scalars in LDS ----
    if (tid < 64) {
        float s0 = lds_s[0][tid], s1 = lds_s[1][tid], s2 = lds_s[2][tid];
        lds_s[0][tid] = __expf(s0 + Eb2[0]);                      // Emod
        float mb = s1 + bb2[0];
        lds_s[1][tid] = mb * mb * (1.f / 40000.f);                // beta
        float mn = s2 + nb2[0];
        lds_s[2][tid] = __expf(mn * mn * (1.f / 40000.f));        // nuv
    }
    __syncthreads();

    // ---- fused scan: wave wid handles rows wid*8 .. wid*8+7 ----
    for (int i = 0; i < 8; ++i) {
        const int rr = wid * 8 + i;
        const int b = brow + rr;
        float Em = lds_s[0][rr], bt = lds_s[1][rr], nv = lds_s[2][rr];
        float cc = DT_ * bt;
        float a  = 1.f - cc;

        size_t base = (size_t)b * T_ + (size_t)l * 8;
        float4 e0 = *(const float4*)(e + base),  e1 = *(const float4*)(e + base + 4);
        float4 d0 = *(const float4*)(ed + base), d1 = *(const float4*)(ed + base + 4);
        float ev[8] = {e0.x, e0.y, e0.z, e0.w, e1.x, e1.y, e1.z, e1.w};
        float dv[8] = {d0.x, d0.y, d0.z, d0.w, d1.x, d1.y, d1.z, d1.w};

        float S = 0.f;
        #pragma unroll
        for (int j = 0; j < 8; j++) S = a * S + ev[j];
        float a2 = a * a, a4 = a2 * a2, A = a4 * a4;

        #pragma unroll
        for (int d = 1; d < 64; d <<= 1) {
            float Su = __shfl_up(S, d);
            float Au = __shfl_up(A, d);
            if (l >= d) { S = Su * A + S; A = Au * A; }
        }
        float Sp = __shfl_up(S, 1);
        float xi = (l == 0) ? 0.f : cc * Sp;

        float st[8], xo[8];
        #pragma unroll
        for (int j = 0; j < 8; j++) {
            xo[j] = xi;
            float qd = ev[j] - xi;
            st[j] = Em * ev[j] + qd + nv * dv[j];
            xi = xi + cc * qd;
        }
        *(float4*)(stress + base)     = (float4){st[0], st[1], st[2], st[3]};
        *(float4*)(stress + base + 4) = (float4){st[4], st[5], st[6], st[7]};
        *(float4*)(xiout + base)      = (float4){xo[0], xo[1], xo[2], xo[3]};
        *(float4*)(xiout + base + 4)  = (float4){xo[4], xo[5], xo[6], xo[7]};
    }
}

extern "C" void kernel_launch(void* const* d_in, const int* in_sizes, int n_in,
                              void* d_out, int out_size, void* d_ws, size_t ws_size,
                              hipStream_t stream) {
    const float* e   = (const float*)d_in[0];
    const float* ed  = (const float*)d_in[1];
    const float* E   = (const float*)d_in[2];
    const float* nu  = (const float*)d_in[3];
    const float* Ew1 = (const float*)d_in[4];
    const float* Eb1 = (const float*)d_in[5];
    const float* Ew2 = (const float*)d_in[6];
    const float* Eb2 = (const float*)d_in[7];
    const float* nw1 = (const float*)d_in[8];
    const float* nb1 = (const float*)d_in[9];
    const float* nw2 = (const float*)d_in[10];
    const float* nb2 = (const float*)d_in[11];
    const float* bw1 = (const float*)d_in[12];
    const float* bb1 = (const float*)d_in[13];
    const float* bw2 = (const float*)d_in[14];
    const float* bb2 = (const float*)d_in[15];

    int B = in_sizes[2] / M_;                       // 32768

    char* ws = (char*)d_ws;
    __hip_bfloat16* Wswz = (__hip_bfloat16*)ws;     // 786432 bytes

    float* stress = (float*)d_out;
    float* xiout  = stress + (size_t)B * T_;

    build_w<<<(1024 * 384 + 255) / 256, 256, 0, stream>>>(Ew1, bw1, nw1, Wswz);
    fused_all<<<B / 64, 512, 0, stream>>>(E, nu, Wswz, Eb1, bb1, nb1,
                                          Ew2, bw2, nw2, Eb2, bb2, nb2,
                                          e, ed, stress, xiout, B);
}